// Round 13
// baseline (59.069 us; speedup 1.0000x reference)
//
#include <hip/hip_runtime.h>

constexpr int J_ = 31;
constexpr int UI = 131072;                 // 256*512 pairs
constexpr size_t D_BYTES = (size_t)UI * 20 * 4;   // 10.5 MB workspace

// ---------------- Phase 1: Sg-only LDS staging, R via coalesced global -------
// Block = 2 waves (128 thr); each wave independently owns 16 pairs x 4 lanes
// (l-split: lane g owns R-component g) and its own 6144 B LDS region:
// per-wave global_load_lds staging + per-wave vmcnt wait, NO __syncthreads.
// 12.3 KB/block -> 13 blocks/CU x 2 waves = ~26 waves/CU (escapes the ~16
// single-wave-workgroup slot cap that pinned r12 at 45% occupancy).
constexpr int PPW   = 16;                  // pairs per wave
constexpr int WPB   = 2;                   // waves per block
constexpr int SGB   = PPW * 93 * 4;        // 5952 B per wave tile
constexpr int SGPAD = 6144;                // staged region (6 x 1KB rounds)
constexpr int NBLK1 = UI / (PPW * WPB);    // 4096 blocks

typedef __attribute__((address_space(1))) const void g1void;
typedef __attribute__((address_space(3))) void s3void;

__global__ __launch_bounds__(WPB * 64) void dqn_phase1(
    const float* __restrict__ Sg, const float* __restrict__ R,
    const float* __restrict__ W1, const float* __restrict__ b1,
    const float* __restrict__ W2, const float* __restrict__ b2,
    float* __restrict__ Dws)
{
    __shared__ float4 sbuf4[WPB * SGPAD / 16];     // 12288 B
    const int tid  = threadIdx.x;
    const int wv   = tid >> 6;                     // wave 0/1
    const int lane = tid & 63;
    const int lp   = lane >> 2;                    // local pair 0..15
    const int g    = lane & 3;

    const int tile = blockIdx.x * WPB + wv;        // this wave's 16-pair tile
    const int pair = tile * PPW + lp;

    char* sb = reinterpret_cast<char*>(sbuf4) + wv * SGPAD;

    // ---- async stage this wave's Sg tile (6 x 1KB rounds, src-clamped) ----
    const char* gS = reinterpret_cast<const char*>(Sg) + (size_t)tile * SGB;
    #pragma unroll
    for (int r = 0; r < 6; ++r) {
        int byte = r * 1024 + lane * 16;
        if (byte > SGB - 16) byte = SGB - 16;      // dup reads; pad absorbs
        __builtin_amdgcn_global_load_lds((g1void*)(gS + byte),
                                         (s3void*)(sb + r * 1024), 16, 0, 0);
    }

    // Uniform embedding weights -> SGPRs (proven scalarization)
    float w10[10], w11[10], w12[10], c1w[10];
    #pragma unroll
    for (int p = 0; p < 10; ++p) {
        w10[p] = W1[p]; w11[p] = W1[10 + p]; w12[p] = W1[20 + p]; c1w[p] = b1[p];
    }

    // R pointer: component g of neighbor j at rr[j*4]
    const float* rr = R + (size_t)pair * 124 + g;
    float q0 = rr[0], q1 = rr[4], q2 = rr[8], q3 = rr[12];   // depth-4 prefetch

    asm volatile("s_waitcnt vmcnt(0)" ::: "memory");   // per-wave: Sg staged
    __builtin_amdgcn_sched_barrier(0);

    const float* sgL = reinterpret_cast<const float*>(sb) + lp * 93;

    float M[10]; float Rsg = 0.f;
    #pragma unroll
    for (int p = 0; p < 10; ++p) M[p] = 0.f;

    auto PROC = [&](int j, float rv) {
        float a0 = sgL[j * 3 + 0];         // 4-lane LDS broadcast
        float a1 = sgL[j * 3 + 1];
        float a2 = sgL[j * 3 + 2];
        #pragma unroll
        for (int p = 0; p < 10; ++p) {
            float t = c1w[p] + a0 * w10[p] + a1 * w11[p] + a2 * w12[p];
            t = t > 0.f ? t : 0.f;         // ReLU
            M[p] += rv * t;
        }
        Rsg += rv;
    };

    // j-blocks of 4 with depth-4 R prefetch (jb = 0..24)
    #pragma unroll 1
    for (int jb = 0; jb < 28; jb += 4) {
        float n0 = rr[(jb + 4) * 4];
        float n1 = rr[(jb + 5) * 4];
        float n2 = rr[(jb + 6) * 4];
        float n3 = (jb + 7 < J_) ? rr[(jb + 7) * 4] : 0.f;
        PROC(jb + 0, q0);
        PROC(jb + 1, q1);
        PROC(jb + 2, q2);
        PROC(jb + 3, q3);
        q0 = n0; q1 = n1; q2 = n2; q3 = n3;
    }
    PROC(28, q0); PROC(29, q1); PROC(30, q2);      // tail j = 28..30

    // T2 row g: T2g[n] = sum_p M[p]*W2[p][n] + Rsg*b2[n]   (uniform -> s_load)
    float T2g[10];
    #pragma unroll
    for (int n = 0; n < 10; ++n) T2g[n] = Rsg * b2[n];
    #pragma unroll
    for (int p = 0; p < 10; ++p) {
        float m = M[p];
        #pragma unroll
        for (int n = 0; n < 10; ++n) T2g[n] += m * W2[p * 10 + n];
    }

    // D[k*10+n] = sum over 4 lanes of T2g[k]*T2g[n]  (T1 == T2^T)
    float D[20];
    #pragma unroll
    for (int k = 0; k < 2; ++k)
        #pragma unroll
        for (int n = 0; n < 10; ++n) D[k * 10 + n] = T2g[k] * T2g[n];
    #pragma unroll
    for (int t = 0; t < 20; ++t) {
        D[t] += __shfl_xor(D[t], 1);
        D[t] += __shfl_xor(D[t], 2);
    }

    // Transposed store, static register indices per g-branch (no scratch).
    float* dw = Dws + pair;
    if (g == 0) {
        dw[0 * UI] = D[0];  dw[1 * UI] = D[1];  dw[2 * UI] = D[2];
        dw[3 * UI] = D[3];  dw[4 * UI] = D[4];
    } else if (g == 1) {
        dw[5 * UI] = D[5];  dw[6 * UI] = D[6];  dw[7 * UI] = D[7];
        dw[8 * UI] = D[8];  dw[9 * UI] = D[9];
    } else if (g == 2) {
        dw[10 * UI] = D[10]; dw[11 * UI] = D[11]; dw[12 * UI] = D[12];
        dw[13 * UI] = D[13]; dw[14 * UI] = D[14];
    } else {
        dw[15 * UI] = D[15]; dw[16 * UI] = D[16]; dw[17 * UI] = D[17];
        dw[18 * UI] = D[18]; dw[19 * UI] = D[19];
    }
}

// ---------------- Phase 2: fit MLP, 4 lanes/pair (proven r12 tail) -----------
__global__ __launch_bounds__(256) void dqn_phase2(
    const float* __restrict__ Dws,
    const float* __restrict__ Wf1, const float* __restrict__ bf1,
    const float* __restrict__ Wf2, const float* __restrict__ bf2,
    const float* __restrict__ Wf3, const float* __restrict__ bf3,
    float* __restrict__ out)
{
    __shared__ float4 wlds4[448];          // 7168 B
    const int tid = threadIdx.x;

    // stage fit weights: WF1@0[640f] WF2@640[1024f] BF1@1664 BF2@1696 WF3@1728 BF3@1760
    {
        if (tid < 160) wlds4[tid] = reinterpret_cast<const float4*>(Wf1)[tid];
        wlds4[160 + tid] = reinterpret_cast<const float4*>(Wf2)[tid];
        if (tid < 8)       wlds4[416 + tid]        = reinterpret_cast<const float4*>(bf1)[tid];
        else if (tid < 16) wlds4[424 + (tid - 8)]  = reinterpret_cast<const float4*>(bf2)[tid - 8];
        else if (tid < 24) wlds4[432 + (tid - 16)] = reinterpret_cast<const float4*>(Wf3)[tid - 16];
        else if (tid == 24) { reinterpret_cast<float*>(wlds4)[1760] = bf3[0]; }
    }
    __syncthreads();

    const int gt   = blockIdx.x * 256 + tid;
    const int pair = gt >> 2;
    const int g    = gt & 3;

    float D[20];
    #pragma unroll
    for (int t = 0; t < 20; ++t) D[t] = Dws[(size_t)t * UI + pair];  // coalesced

    const float* wl = reinterpret_cast<const float*>(wlds4);

    float F[8];
    {
        const float4* b4 = reinterpret_cast<const float4*>(wl + 1664 + g * 8);
        float4 x = b4[0], y = b4[1];
        F[0]=x.x; F[1]=x.y; F[2]=x.z; F[3]=x.w; F[4]=y.x; F[5]=y.y; F[6]=y.z; F[7]=y.w;
    }
    #pragma unroll
    for (int kk = 0; kk < 20; ++kk) {
        float d = D[kk];
        const float4* w4 = reinterpret_cast<const float4*>(wl + kk * 32 + g * 8);
        float4 wa = w4[0], wb = w4[1];
        F[0] += d * wa.x; F[1] += d * wa.y; F[2] += d * wa.z; F[3] += d * wa.w;
        F[4] += d * wb.x; F[5] += d * wb.y; F[6] += d * wb.z; F[7] += d * wb.w;
    }
    #pragma unroll
    for (int i = 0; i < 8; ++i) F[i] = F[i] > 0.f ? F[i] : 0.f;

    // gather full f1 (static-index butterfly)
    float P[8];
    #pragma unroll
    for (int i = 0; i < 8; ++i) P[i] = __shfl_xor(F[i], 1);
    const bool odd = (g & 1);
    float lo[16];
    #pragma unroll
    for (int i = 0; i < 8; ++i) {
        lo[i]     = odd ? P[i] : F[i];
        lo[8 + i] = odd ? F[i] : P[i];
    }
    float hi[16];
    #pragma unroll
    for (int i = 0; i < 16; ++i) hi[i] = __shfl_xor(lo[i], 2);
    const bool up = (g & 2);
    float f1a[32];
    #pragma unroll
    for (int i = 0; i < 16; ++i) {
        f1a[i]      = up ? hi[i] : lo[i];
        f1a[16 + i] = up ? lo[i] : hi[i];
    }

    float G[8];
    {
        const float4* b4 = reinterpret_cast<const float4*>(wl + 1696 + g * 8);
        float4 x = b4[0], y = b4[1];
        G[0]=x.x; G[1]=x.y; G[2]=x.z; G[3]=x.w; G[4]=y.x; G[5]=y.y; G[6]=y.z; G[7]=y.w;
    }
    #pragma unroll
    for (int kk = 0; kk < 32; ++kk) {
        float d = f1a[kk];
        const float4* w4 = reinterpret_cast<const float4*>(wl + 640 + kk * 32 + g * 8);
        float4 wa = w4[0], wb = w4[1];
        G[0] += d * wa.x; G[1] += d * wa.y; G[2] += d * wa.z; G[3] += d * wa.w;
        G[4] += d * wb.x; G[5] += d * wb.y; G[6] += d * wb.z; G[7] += d * wb.w;
    }
    #pragma unroll
    for (int i = 0; i < 8; ++i) G[i] = G[i] > 0.f ? G[i] : 0.f;

    float qp;
    {
        const float4* w4 = reinterpret_cast<const float4*>(wl + 1728 + g * 8);
        float4 wa = w4[0], wb = w4[1];
        qp = G[0]*wa.x + G[1]*wa.y + G[2]*wa.z + G[3]*wa.w
           + G[4]*wb.x + G[5]*wb.y + G[6]*wb.z + G[7]*wb.w;
    }
    qp += __shfl_xor(qp, 1);
    qp += __shfl_xor(qp, 2);
    float q = qp + wl[1760];

    if (g == 0) out[pair] = q;
}

// ---------------- Fallback: known-good fused v1 (if ws too small) ------------
struct Nb1 { float s0, s1, s2; float4 r; };
__device__ __forceinline__ Nb1 load_nb1(const float* __restrict__ sg,
                                        const float* __restrict__ rr, int j) {
    Nb1 d;
    d.s0 = sg[j * 3 + 0]; d.s1 = sg[j * 3 + 1]; d.s2 = sg[j * 3 + 2];
    d.r = *reinterpret_cast<const float4*>(rr + j * 4);
    return d;
}
__global__ __launch_bounds__(256, 2) void dqn_fused_fb(
    const float* __restrict__ Sg,  const float* __restrict__ R,
    const float* __restrict__ W1,  const float* __restrict__ b1,
    const float* __restrict__ W2,  const float* __restrict__ b2,
    const float* __restrict__ Wf1, const float* __restrict__ bf1,
    const float* __restrict__ Wf2, const float* __restrict__ bf2,
    const float* __restrict__ Wf3, const float* __restrict__ bf3,
    float* __restrict__ out)
{
    const int pair = blockIdx.x * 256 + threadIdx.x;
    const float* sg = Sg + (size_t)pair * (J_ * 3);
    const float* rr = R  + (size_t)pair * (J_ * 4);
    float w1[3][10], c1[10];
    #pragma unroll
    for (int k = 0; k < 3; ++k)
        #pragma unroll
        for (int p = 0; p < 10; ++p) w1[k][p] = W1[k * 10 + p];
    #pragma unroll
    for (int p = 0; p < 10; ++p) c1[p] = b1[p];
    float M[4][10]; float Rs[4] = {0.f,0.f,0.f,0.f};
    #pragma unroll
    for (int l = 0; l < 4; ++l)
        #pragma unroll
        for (int p = 0; p < 10; ++p) M[l][p] = 0.f;
    #pragma unroll 1
    for (int j = 0; j < J_; ++j) {
        Nb1 nb = load_nb1(sg, rr, j);
        float h[10];
        #pragma unroll
        for (int p = 0; p < 10; ++p) {
            float t = c1[p] + nb.s0*w1[0][p] + nb.s1*w1[1][p] + nb.s2*w1[2][p];
            h[p] = t > 0.f ? t : 0.f;
        }
        Rs[0]+=nb.r.x; Rs[1]+=nb.r.y; Rs[2]+=nb.r.z; Rs[3]+=nb.r.w;
        #pragma unroll
        for (int p = 0; p < 10; ++p) {
            M[0][p]+=nb.r.x*h[p]; M[1][p]+=nb.r.y*h[p];
            M[2][p]+=nb.r.z*h[p]; M[3][p]+=nb.r.w*h[p];
        }
    }
    float T2[4][10];
    #pragma unroll
    for (int l = 0; l < 4; ++l)
        #pragma unroll
        for (int n = 0; n < 10; ++n) T2[l][n] = Rs[l] * b2[n];
    #pragma unroll
    for (int p = 0; p < 10; ++p) {
        #pragma unroll
        for (int l = 0; l < 4; ++l) {
            float m = M[l][p];
            #pragma unroll
            for (int n = 0; n < 10; ++n) T2[l][n] += m * W2[p * 10 + n];
        }
    }
    float D[20];
    #pragma unroll
    for (int k = 0; k < 2; ++k)
        #pragma unroll
        for (int n = 0; n < 10; ++n)
            D[k*10+n] = T2[0][k]*T2[0][n] + T2[1][k]*T2[1][n]
                      + T2[2][k]*T2[2][n] + T2[3][k]*T2[3][n];
    float f1[32];
    #pragma unroll
    for (int o = 0; o < 32; ++o) f1[o] = bf1[o];
    #pragma unroll
    for (int kk = 0; kk < 20; ++kk) {
        const float4* wrow = reinterpret_cast<const float4*>(Wf1 + kk * 32);
        float d = D[kk];
        #pragma unroll
        for (int v = 0; v < 8; ++v) {
            float4 w = wrow[v];
            f1[4*v+0]+=d*w.x; f1[4*v+1]+=d*w.y; f1[4*v+2]+=d*w.z; f1[4*v+3]+=d*w.w;
        }
    }
    #pragma unroll
    for (int o = 0; o < 32; ++o) f1[o] = f1[o] > 0.f ? f1[o] : 0.f;
    float f2[32];
    #pragma unroll
    for (int o = 0; o < 32; ++o) f2[o] = bf2[o];
    #pragma unroll
    for (int kk = 0; kk < 32; ++kk) {
        const float4* wrow = reinterpret_cast<const float4*>(Wf2 + kk * 32);
        float d = f1[kk];
        #pragma unroll
        for (int v = 0; v < 8; ++v) {
            float4 w = wrow[v];
            f2[4*v+0]+=d*w.x; f2[4*v+1]+=d*w.y; f2[4*v+2]+=d*w.z; f2[4*v+3]+=d*w.w;
        }
    }
    #pragma unroll
    for (int o = 0; o < 32; ++o) f2[o] = f2[o] > 0.f ? f2[o] : 0.f;
    float q = bf3[0];
    #pragma unroll
    for (int o = 0; o < 32; o += 4) {
        float4 w = *reinterpret_cast<const float4*>(Wf3 + o);
        q += f2[o+0]*w.x + f2[o+1]*w.y + f2[o+2]*w.z + f2[o+3]*w.w;
    }
    out[pair] = q;
}

extern "C" void kernel_launch(void* const* d_in, const int* in_sizes, int n_in,
                              void* d_out, int out_size, void* d_ws, size_t ws_size,
                              hipStream_t stream) {
    const float* Sg  = (const float*)d_in[0];
    const float* R   = (const float*)d_in[1];
    const float* W1  = (const float*)d_in[2];
    const float* b1  = (const float*)d_in[3];
    const float* W2  = (const float*)d_in[4];
    const float* b2  = (const float*)d_in[5];
    const float* Wf1 = (const float*)d_in[6];
    const float* bf1 = (const float*)d_in[7];
    const float* Wf2 = (const float*)d_in[8];
    const float* bf2 = (const float*)d_in[9];
    const float* Wf3 = (const float*)d_in[10];
    const float* bf3 = (const float*)d_in[11];
    float* out = (float*)d_out;

    if (ws_size >= D_BYTES) {
        float* Dws = (float*)d_ws;
        dqn_phase1<<<dim3(NBLK1), dim3(WPB * 64), 0, stream>>>(
            Sg, R, W1, b1, W2, b2, Dws);
        dqn_phase2<<<dim3((UI * 4) / 256), dim3(256), 0, stream>>>(
            Dws, Wf1, bf1, Wf2, bf2, Wf3, bf3, out);
    } else {
        dqn_fused_fb<<<dim3(UI / 256), dim3(256), 0, stream>>>(
            Sg, R, W1, b1, W2, b2, Wf1, bf1, Wf2, bf2, Wf3, bf3, out);
    }
}

// Round 14
// 44.470 us; speedup vs baseline: 1.3283x; 1.3283x over previous
//
#include <hip/hip_runtime.h>

constexpr int J_ = 31;
constexpr int UI = 131072;                 // 256*512 pairs
constexpr size_t D_BYTES = (size_t)UI * 20 * 4;   // 10.5 MB workspace

// ---------------- Phase 1: j-split + DPP quad reduce -------------------------
// Block = 1 wave = 16 pairs x 4 lanes. Lane g of pair lp handles neighbors
// j = g, g+4, ..., computing h ONCE per neighbor (no 4x l-split redundancy)
// and accumulating per-lane partials M[4][10], Rs[4]. Quad all-reduce via
// DPP quad_perm adds (pure VALU). Sg async-staged in LDS (proven r12);
// R read from global as per-lane float4 (j-split, depth-2 block prefetch).
constexpr int PPB   = 16;
constexpr int SGB   = PPB * 93 * 4;        // 5952 B
constexpr int NBLK1 = UI / PPB;            // 8192 blocks

typedef __attribute__((address_space(1))) const void g1void;
typedef __attribute__((address_space(3))) void s3void;

__device__ __forceinline__ float qsum(float x) {
    // sum over each quad of lanes: xor1 then xor2 via DPP quad_perm (VALU-only)
    int a = __builtin_amdgcn_update_dpp(0, __float_as_int(x), 0xB1, 0xF, 0xF, true);
    x += __int_as_float(a);
    int b = __builtin_amdgcn_update_dpp(0, __float_as_int(x), 0x4E, 0xF, 0xF, true);
    x += __int_as_float(b);
    return x;
}

__global__ __launch_bounds__(64) void dqn_phase1(
    const float* __restrict__ Sg, const float* __restrict__ R,
    const float* __restrict__ W1, const float* __restrict__ b1,
    const float* __restrict__ W2, const float* __restrict__ b2,
    float* __restrict__ Dws)
{
    __shared__ float4 sbuf4[384];          // 6144 B (5952 used + pad)
    char* sb = reinterpret_cast<char*>(sbuf4);

    const int tid  = threadIdx.x;          // == lane (single wave)
    const int lp   = tid >> 2;             // local pair 0..15
    const int g    = tid & 3;
    const int pair = blockIdx.x * PPB + lp;

    // ---- async stage Sg tile (6 x 1KB rounds, source-clamped tail) ----
    const char* gS = reinterpret_cast<const char*>(Sg) + (size_t)blockIdx.x * SGB;
    #pragma unroll
    for (int r = 0; r < 6; ++r) {
        int byte = r * 1024 + tid * 16;
        if (byte > SGB - 16) byte = SGB - 16;      // dup reads; LDS pad absorbs
        __builtin_amdgcn_global_load_lds((g1void*)(gS + byte),
                                         (s3void*)(sb + r * 1024), 16, 0, 0);
    }

    // Uniform embedding weights -> SGPRs
    float w10[10], w11[10], w12[10], c1w[10];
    #pragma unroll
    for (int p = 0; p < 10; ++p) {
        w10[p] = W1[p]; w11[p] = W1[10 + p]; w12[p] = W1[20 + p]; c1w[p] = b1[p];
    }

    // R row as float4[31]; lane g owns neighbors jb+g. Depth-2 block prefetch.
    const float4* rv = reinterpret_cast<const float4*>(R + (size_t)pair * 124);
    float4 rqA = rv[g];
    float4 rqB = rv[4 + g];

    asm volatile("s_waitcnt vmcnt(0)" ::: "memory");   // Sg staged (+ rqA/rqB)
    __builtin_amdgcn_sched_barrier(0);

    const float* sgL = reinterpret_cast<const float*>(sb) + lp * 93;

    float M0[10], M1[10], M2[10], M3[10];
    float4 Rs = {0.f, 0.f, 0.f, 0.f};
    #pragma unroll
    for (int p = 0; p < 10; ++p) { M0[p]=0.f; M1[p]=0.f; M2[p]=0.f; M3[p]=0.f; }

    auto PROC = [&](int j, const float4& r4) {
        float s0 = sgL[j * 3 + 0];
        float s1 = sgL[j * 3 + 1];
        float s2 = sgL[j * 3 + 2];
        #pragma unroll
        for (int p = 0; p < 10; ++p) {
            float t = c1w[p] + s0 * w10[p] + s1 * w11[p] + s2 * w12[p];
            t = t > 0.f ? t : 0.f;         // ReLU (h computed ONCE per neighbor)
            M0[p] += r4.x * t;
            M1[p] += r4.y * t;
            M2[p] += r4.z * t;
            M3[p] += r4.w * t;
        }
        Rs.x += r4.x; Rs.y += r4.y; Rs.z += r4.z; Rs.w += r4.w;
    };

    // j-blocks: lane g handles j = jb+g. 0..27 full; 28+g masked for g==3.
    #pragma unroll 1
    for (int jb = 0; jb < 16; jb += 8) {
        float4 nA = rv[jb +  8 + g];
        float4 nB = rv[jb + 12 + g];
        PROC(jb + g,     rqA);
        PROC(jb + 4 + g, rqB);
        rqA = nA; rqB = nB;
    }
    {   // jb = 16, 20
        float4 nA = rv[24 + g];
        int jt = 28 + g;
        float4 nB = rv[jt < J_ ? jt : (J_ - 1)];   // clamped dup for g==3
        PROC(16 + g, rqA);
        PROC(20 + g, rqB);
        rqA = nA; rqB = nB;
    }
    PROC(24 + g, rqA);
    {   // tail j = 28+g, mask lane g==3 (j==31): r=0; sg read hits LDS pad
        float m = (g < 3) ? 1.f : 0.f;
        rqB.x *= m; rqB.y *= m; rqB.z *= m; rqB.w *= m;
        PROC(28 + g, rqB);
    }

    // ---- quad all-reduce M[4][10], Rs[4] (DPP, pure VALU) ----
    #pragma unroll
    for (int p = 0; p < 10; ++p) {
        M0[p] = qsum(M0[p]); M1[p] = qsum(M1[p]);
        M2[p] = qsum(M2[p]); M3[p] = qsum(M3[p]);
    }
    Rs.x = qsum(Rs.x); Rs.y = qsum(Rs.y); Rs.z = qsum(Rs.z); Rs.w = qsum(Rs.w);

    // Lane g selects its row (static cndmask chains)
    float Mg[10];
    #pragma unroll
    for (int p = 0; p < 10; ++p)
        Mg[p] = (g == 0) ? M0[p] : (g == 1) ? M1[p] : (g == 2) ? M2[p] : M3[p];
    float Rsg = (g == 0) ? Rs.x : (g == 1) ? Rs.y : (g == 2) ? Rs.z : Rs.w;

    // T2 row g: T2g[n] = sum_p Mg[p]*W2[p][n] + Rsg*b2[n]   (uniform -> s_load)
    float T2g[10];
    #pragma unroll
    for (int n = 0; n < 10; ++n) T2g[n] = Rsg * b2[n];
    #pragma unroll
    for (int p = 0; p < 10; ++p) {
        float m = Mg[p];
        #pragma unroll
        for (int n = 0; n < 10; ++n) T2g[n] += m * W2[p * 10 + n];
    }

    // D[k*10+n] = sum over 4 lanes of T2g[k]*T2g[n]  (T1 == T2^T)
    float D[20];
    #pragma unroll
    for (int k = 0; k < 2; ++k)
        #pragma unroll
        for (int n = 0; n < 10; ++n) D[k * 10 + n] = T2g[k] * T2g[n];
    #pragma unroll
    for (int t = 0; t < 20; ++t) D[t] = qsum(D[t]);

    // Transposed store, static register indices per g-branch (no scratch).
    float* dw = Dws + pair;
    if (g == 0) {
        dw[0 * UI] = D[0];  dw[1 * UI] = D[1];  dw[2 * UI] = D[2];
        dw[3 * UI] = D[3];  dw[4 * UI] = D[4];
    } else if (g == 1) {
        dw[5 * UI] = D[5];  dw[6 * UI] = D[6];  dw[7 * UI] = D[7];
        dw[8 * UI] = D[8];  dw[9 * UI] = D[9];
    } else if (g == 2) {
        dw[10 * UI] = D[10]; dw[11 * UI] = D[11]; dw[12 * UI] = D[12];
        dw[13 * UI] = D[13]; dw[14 * UI] = D[14];
    } else {
        dw[15 * UI] = D[15]; dw[16 * UI] = D[16]; dw[17 * UI] = D[17];
        dw[18 * UI] = D[18]; dw[19 * UI] = D[19];
    }
}

// ---------------- Phase 2: fit MLP, 4 lanes/pair (proven r12 tail) -----------
__global__ __launch_bounds__(256) void dqn_phase2(
    const float* __restrict__ Dws,
    const float* __restrict__ Wf1, const float* __restrict__ bf1,
    const float* __restrict__ Wf2, const float* __restrict__ bf2,
    const float* __restrict__ Wf3, const float* __restrict__ bf3,
    float* __restrict__ out)
{
    __shared__ float4 wlds4[448];          // 7168 B
    const int tid = threadIdx.x;

    // stage fit weights: WF1@0[640f] WF2@640[1024f] BF1@1664 BF2@1696 WF3@1728 BF3@1760
    {
        if (tid < 160) wlds4[tid] = reinterpret_cast<const float4*>(Wf1)[tid];
        wlds4[160 + tid] = reinterpret_cast<const float4*>(Wf2)[tid];
        if (tid < 8)       wlds4[416 + tid]        = reinterpret_cast<const float4*>(bf1)[tid];
        else if (tid < 16) wlds4[424 + (tid - 8)]  = reinterpret_cast<const float4*>(bf2)[tid - 8];
        else if (tid < 24) wlds4[432 + (tid - 16)] = reinterpret_cast<const float4*>(Wf3)[tid - 16];
        else if (tid == 24) { reinterpret_cast<float*>(wlds4)[1760] = bf3[0]; }
    }
    __syncthreads();

    const int gt   = blockIdx.x * 256 + tid;
    const int pair = gt >> 2;
    const int g    = gt & 3;

    float D[20];
    #pragma unroll
    for (int t = 0; t < 20; ++t) D[t] = Dws[(size_t)t * UI + pair];  // coalesced

    const float* wl = reinterpret_cast<const float*>(wlds4);

    float F[8];
    {
        const float4* b4 = reinterpret_cast<const float4*>(wl + 1664 + g * 8);
        float4 x = b4[0], y = b4[1];
        F[0]=x.x; F[1]=x.y; F[2]=x.z; F[3]=x.w; F[4]=y.x; F[5]=y.y; F[6]=y.z; F[7]=y.w;
    }
    #pragma unroll
    for (int kk = 0; kk < 20; ++kk) {
        float d = D[kk];
        const float4* w4 = reinterpret_cast<const float4*>(wl + kk * 32 + g * 8);
        float4 wa = w4[0], wb = w4[1];
        F[0] += d * wa.x; F[1] += d * wa.y; F[2] += d * wa.z; F[3] += d * wa.w;
        F[4] += d * wb.x; F[5] += d * wb.y; F[6] += d * wb.z; F[7] += d * wb.w;
    }
    #pragma unroll
    for (int i = 0; i < 8; ++i) F[i] = F[i] > 0.f ? F[i] : 0.f;

    // gather full f1 (static-index butterfly)
    float P[8];
    #pragma unroll
    for (int i = 0; i < 8; ++i) P[i] = __shfl_xor(F[i], 1);
    const bool odd = (g & 1);
    float lo[16];
    #pragma unroll
    for (int i = 0; i < 8; ++i) {
        lo[i]     = odd ? P[i] : F[i];
        lo[8 + i] = odd ? F[i] : P[i];
    }
    float hi[16];
    #pragma unroll
    for (int i = 0; i < 16; ++i) hi[i] = __shfl_xor(lo[i], 2);
    const bool up = (g & 2);
    float f1a[32];
    #pragma unroll
    for (int i = 0; i < 16; ++i) {
        f1a[i]      = up ? hi[i] : lo[i];
        f1a[16 + i] = up ? lo[i] : hi[i];
    }

    float G[8];
    {
        const float4* b4 = reinterpret_cast<const float4*>(wl + 1696 + g * 8);
        float4 x = b4[0], y = b4[1];
        G[0]=x.x; G[1]=x.y; G[2]=x.z; G[3]=x.w; G[4]=y.x; G[5]=y.y; G[6]=y.z; G[7]=y.w;
    }
    #pragma unroll
    for (int kk = 0; kk < 32; ++kk) {
        float d = f1a[kk];
        const float4* w4 = reinterpret_cast<const float4*>(wl + 640 + kk * 32 + g * 8);
        float4 wa = w4[0], wb = w4[1];
        G[0] += d * wa.x; G[1] += d * wa.y; G[2] += d * wa.z; G[3] += d * wa.w;
        G[4] += d * wb.x; G[5] += d * wb.y; G[6] += d * wb.z; G[7] += d * wb.w;
    }
    #pragma unroll
    for (int i = 0; i < 8; ++i) G[i] = G[i] > 0.f ? G[i] : 0.f;

    float qp;
    {
        const float4* w4 = reinterpret_cast<const float4*>(wl + 1728 + g * 8);
        float4 wa = w4[0], wb = w4[1];
        qp = G[0]*wa.x + G[1]*wa.y + G[2]*wa.z + G[3]*wa.w
           + G[4]*wb.x + G[5]*wb.y + G[6]*wb.z + G[7]*wb.w;
    }
    qp += __shfl_xor(qp, 1);
    qp += __shfl_xor(qp, 2);
    float q = qp + wl[1760];

    if (g == 0) out[pair] = q;
}

// ---------------- Fallback: known-good fused v1 (if ws too small) ------------
struct Nb1 { float s0, s1, s2; float4 r; };
__device__ __forceinline__ Nb1 load_nb1(const float* __restrict__ sg,
                                        const float* __restrict__ rr, int j) {
    Nb1 d;
    d.s0 = sg[j * 3 + 0]; d.s1 = sg[j * 3 + 1]; d.s2 = sg[j * 3 + 2];
    d.r = *reinterpret_cast<const float4*>(rr + j * 4);
    return d;
}
__global__ __launch_bounds__(256, 2) void dqn_fused_fb(
    const float* __restrict__ Sg,  const float* __restrict__ R,
    const float* __restrict__ W1,  const float* __restrict__ b1,
    const float* __restrict__ W2,  const float* __restrict__ b2,
    const float* __restrict__ Wf1, const float* __restrict__ bf1,
    const float* __restrict__ Wf2, const float* __restrict__ bf2,
    const float* __restrict__ Wf3, const float* __restrict__ bf3,
    float* __restrict__ out)
{
    const int pair = blockIdx.x * 256 + threadIdx.x;
    const float* sg = Sg + (size_t)pair * (J_ * 3);
    const float* rr = R  + (size_t)pair * (J_ * 4);
    float w1[3][10], c1[10];
    #pragma unroll
    for (int k = 0; k < 3; ++k)
        #pragma unroll
        for (int p = 0; p < 10; ++p) w1[k][p] = W1[k * 10 + p];
    #pragma unroll
    for (int p = 0; p < 10; ++p) c1[p] = b1[p];
    float M[4][10]; float Rs[4] = {0.f,0.f,0.f,0.f};
    #pragma unroll
    for (int l = 0; l < 4; ++l)
        #pragma unroll
        for (int p = 0; p < 10; ++p) M[l][p] = 0.f;
    #pragma unroll 1
    for (int j = 0; j < J_; ++j) {
        Nb1 nb = load_nb1(sg, rr, j);
        float h[10];
        #pragma unroll
        for (int p = 0; p < 10; ++p) {
            float t = c1[p] + nb.s0*w1[0][p] + nb.s1*w1[1][p] + nb.s2*w1[2][p];
            h[p] = t > 0.f ? t : 0.f;
        }
        Rs[0]+=nb.r.x; Rs[1]+=nb.r.y; Rs[2]+=nb.r.z; Rs[3]+=nb.r.w;
        #pragma unroll
        for (int p = 0; p < 10; ++p) {
            M[0][p]+=nb.r.x*h[p]; M[1][p]+=nb.r.y*h[p];
            M[2][p]+=nb.r.z*h[p]; M[3][p]+=nb.r.w*h[p];
        }
    }
    float T2[4][10];
    #pragma unroll
    for (int l = 0; l < 4; ++l)
        #pragma unroll
        for (int n = 0; n < 10; ++n) T2[l][n] = Rs[l] * b2[n];
    #pragma unroll
    for (int p = 0; p < 10; ++p) {
        #pragma unroll
        for (int l = 0; l < 4; ++l) {
            float m = M[l][p];
            #pragma unroll
            for (int n = 0; n < 10; ++n) T2[l][n] += m * W2[p * 10 + n];
        }
    }
    float D[20];
    #pragma unroll
    for (int k = 0; k < 2; ++k)
        #pragma unroll
        for (int n = 0; n < 10; ++n)
            D[k*10+n] = T2[0][k]*T2[0][n] + T2[1][k]*T2[1][n]
                      + T2[2][k]*T2[2][n] + T2[3][k]*T2[3][n];
    float f1[32];
    #pragma unroll
    for (int o = 0; o < 32; ++o) f1[o] = bf1[o];
    #pragma unroll
    for (int kk = 0; kk < 20; ++kk) {
        const float4* wrow = reinterpret_cast<const float4*>(Wf1 + kk * 32);
        float d = D[kk];
        #pragma unroll
        for (int v = 0; v < 8; ++v) {
            float4 w = wrow[v];
            f1[4*v+0]+=d*w.x; f1[4*v+1]+=d*w.y; f1[4*v+2]+=d*w.z; f1[4*v+3]+=d*w.w;
        }
    }
    #pragma unroll
    for (int o = 0; o < 32; ++o) f1[o] = f1[o] > 0.f ? f1[o] : 0.f;
    float f2[32];
    #pragma unroll
    for (int o = 0; o < 32; ++o) f2[o] = bf2[o];
    #pragma unroll
    for (int kk = 0; kk < 32; ++kk) {
        const float4* wrow = reinterpret_cast<const float4*>(Wf2 + kk * 32);
        float d = f1[kk];
        #pragma unroll
        for (int v = 0; v < 8; ++v) {
            float4 w = wrow[v];
            f2[4*v+0]+=d*w.x; f2[4*v+1]+=d*w.y; f2[4*v+2]+=d*w.z; f2[4*v+3]+=d*w.w;
        }
    }
    #pragma unroll
    for (int o = 0; o < 32; ++o) f2[o] = f2[o] > 0.f ? f2[o] : 0.f;
    float q = bf3[0];
    #pragma unroll
    for (int o = 0; o < 32; o += 4) {
        float4 w = *reinterpret_cast<const float4*>(Wf3 + o);
        q += f2[o+0]*w.x + f2[o+1]*w.y + f2[o+2]*w.z + f2[o+3]*w.w;
    }
    out[pair] = q;
}

extern "C" void kernel_launch(void* const* d_in, const int* in_sizes, int n_in,
                              void* d_out, int out_size, void* d_ws, size_t ws_size,
                              hipStream_t stream) {
    const float* Sg  = (const float*)d_in[0];
    const float* R   = (const float*)d_in[1];
    const float* W1  = (const float*)d_in[2];
    const float* b1  = (const float*)d_in[3];
    const float* W2  = (const float*)d_in[4];
    const float* b2  = (const float*)d_in[5];
    const float* Wf1 = (const float*)d_in[6];
    const float* bf1 = (const float*)d_in[7];
    const float* Wf2 = (const float*)d_in[8];
    const float* bf2 = (const float*)d_in[9];
    const float* Wf3 = (const float*)d_in[10];
    const float* bf3 = (const float*)d_in[11];
    float* out = (float*)d_out;

    if (ws_size >= D_BYTES) {
        float* Dws = (float*)d_ws;
        dqn_phase1<<<dim3(NBLK1), dim3(64), 0, stream>>>(
            Sg, R, W1, b1, W2, b2, Dws);
        dqn_phase2<<<dim3((UI * 4) / 256), dim3(256), 0, stream>>>(
            Dws, Wf1, bf1, Wf2, bf2, Wf3, bf3, out);
    } else {
        dqn_fused_fb<<<dim3(UI / 256), dim3(256), 0, stream>>>(
            Sg, R, W1, b1, W2, b2, Wf1, bf1, Wf2, bf2, Wf3, bf3, out);
    }
}